// Round 1
// baseline (2217.361 us; speedup 1.0000x reference)
//
#include <hip/hip_runtime.h>

#define N_NODES 100000
#define N_EDGES 1600000
#define N_GRAPHS 128
#define EMBED 32
#define HID 64

// ---------------- workspace layout (floats) ----------------
// zeroed each launch:  [cnt N][agg32 32N][agg64 64N][pooled 64G][gcnt G]
// persistent scratch:  [x0 32N][h1 64N]
// total = 193N + 65G floats  ~= 77.3 MB

// x0[n] = embed_table[node_ids[n]]   (8 lanes/node, float4)
__global__ void k_embed(const int* __restrict__ ids,
                        const float* __restrict__ table,
                        float* __restrict__ x0) {
    int gid = blockIdx.x * blockDim.x + threadIdx.x;
    if (gid >= N_NODES * 8) return;
    int n = gid >> 3, q = gid & 7;
    int id = ids[n];
    float4 v = *(const float4*)(table + id * EMBED + q * 4);
    *(float4*)(x0 + n * EMBED + q * 4) = v;
}

// conv1 aggregation: agg32[dst] += x0[src]; cnt[dst] += 1   (8 lanes/edge)
__global__ void k_scatter1(const int* __restrict__ src, const int* __restrict__ dst,
                           const float* __restrict__ x0,
                           float* __restrict__ agg32, float* __restrict__ cnt) {
    int gid = blockIdx.x * blockDim.x + threadIdx.x;
    if (gid >= N_EDGES * 8) return;
    int e = gid >> 3, q = gid & 7;
    int s = src[e], d = dst[e];
    float4 v = *(const float4*)(x0 + s * EMBED + q * 4);
    float* p = agg32 + d * EMBED + q * 4;
    unsafeAtomicAdd(p + 0, v.x);
    unsafeAtomicAdd(p + 1, v.y);
    unsafeAtomicAdd(p + 2, v.z);
    unsafeAtomicAdd(p + 3, v.w);
    if (q == 0) unsafeAtomicAdd(cnt + d, 1.0f);
}

// conv1 update: h1[n] = relu(mean @ W_l.T + x0 @ W_r.T + b)
// 4 nodes/block (64 lanes each); weights in LDS, stride-33 padded.
__global__ void k_update1(const float* __restrict__ agg32, const float* __restrict__ cnt,
                          const float* __restrict__ x0,
                          const float* __restrict__ W_l, const float* __restrict__ W_r,
                          const float* __restrict__ b, float* __restrict__ h1) {
    __shared__ float sWl[64 * 33];
    __shared__ float sWr[64 * 33];
    __shared__ float srow[4][64];   // [group][ mean(32) | x(32) ]
    for (int i = threadIdx.x; i < 64 * 32; i += 256) {
        int o = i >> 5, k = i & 31;
        sWl[o * 33 + k] = W_l[i];
        sWr[o * 33 + k] = W_r[i];
    }
    int grp = threadIdx.x >> 6, lane = threadIdx.x & 63;
    int n = blockIdx.x * 4 + grp;   // N_NODES % 4 == 0, always valid
    if (lane < 32) {
        float r = 1.0f / fmaxf(cnt[n], 1.0f);
        srow[grp][lane] = agg32[n * EMBED + lane] * r;
    } else {
        srow[grp][lane] = x0[n * EMBED + lane - 32];
    }
    __syncthreads();
    float sum = b[lane];
    #pragma unroll
    for (int k = 0; k < 32; ++k) {
        sum += srow[grp][k]      * sWl[lane * 33 + k];
        sum += srow[grp][32 + k] * sWr[lane * 33 + k];
    }
    h1[n * HID + lane] = fmaxf(sum, 0.0f);
}

// conv2 aggregation: agg64[dst] += h1[src]   (16 lanes/edge)
__global__ void k_scatter2(const int* __restrict__ src, const int* __restrict__ dst,
                           const float* __restrict__ h1, float* __restrict__ agg64) {
    int gid = blockIdx.x * blockDim.x + threadIdx.x;
    if (gid >= N_EDGES * 16) return;
    int e = gid >> 4, q = gid & 15;
    int s = src[e], d = dst[e];
    float4 v = *(const float4*)(h1 + s * HID + q * 4);
    float* p = agg64 + d * HID + q * 4;
    unsafeAtomicAdd(p + 0, v.x);
    unsafeAtomicAdd(p + 1, v.y);
    unsafeAtomicAdd(p + 2, v.z);
    unsafeAtomicAdd(p + 3, v.w);
}

// conv2 update (in-place: agg64 row -> h2 row)
__global__ void k_update2(float* __restrict__ agg64, const float* __restrict__ cnt,
                          const float* __restrict__ h1,
                          const float* __restrict__ W_l, const float* __restrict__ W_r,
                          const float* __restrict__ b) {
    __shared__ float sWl[64 * 65];
    __shared__ float sWr[64 * 65];
    __shared__ float srow[4][128];  // [group][ mean(64) | h1(64) ]
    for (int i = threadIdx.x; i < 64 * 64; i += 256) {
        int o = i >> 6, k = i & 63;
        sWl[o * 65 + k] = W_l[i];
        sWr[o * 65 + k] = W_r[i];
    }
    int grp = threadIdx.x >> 6, lane = threadIdx.x & 63;
    int n = blockIdx.x * 4 + grp;
    float r = 1.0f / fmaxf(cnt[n], 1.0f);
    srow[grp][lane]      = agg64[n * HID + lane] * r;
    srow[grp][64 + lane] = h1[n * HID + lane];
    __syncthreads();
    float sum = b[lane];
    #pragma unroll
    for (int k = 0; k < 64; ++k) {
        sum += srow[grp][k]      * sWl[lane * 65 + k];
        sum += srow[grp][64 + k] * sWr[lane * 65 + k];
    }
    agg64[n * HID + lane] = fmaxf(sum, 0.0f);
}

// mean pool: batch is sorted -> run-length accumulate per 64-lane group slice
__global__ void k_pool(const float* __restrict__ h2, const int* __restrict__ batch,
                       float* __restrict__ pooled, float* __restrict__ gcnt) {
    const int NGROUPS = 8192;
    int grp = blockIdx.x * (blockDim.x >> 6) + (threadIdx.x >> 6);
    int lane = threadIdx.x & 63;
    int per = (N_NODES + NGROUPS - 1) / NGROUPS;
    int start = grp * per;
    if (start >= N_NODES) return;
    int end = start + per; if (end > N_NODES) end = N_NODES;
    float acc = 0.0f, c = 0.0f;
    int cur = batch[start];
    for (int n = start; n < end; ++n) {
        int bb = batch[n];
        if (bb != cur) {
            unsafeAtomicAdd(&pooled[cur * HID + lane], acc);
            if (lane == 0) unsafeAtomicAdd(&gcnt[cur], c);
            acc = 0.0f; c = 0.0f; cur = bb;
        }
        acc += h2[n * HID + lane];
        c += 1.0f;
    }
    unsafeAtomicAdd(&pooled[cur * HID + lane], acc);
    if (lane == 0) unsafeAtomicAdd(&gcnt[cur], c);
}

// out[g][c] = (pooled[g]/cnt) . W_lin[c] + b_lin[c]
__global__ void k_final(const float* __restrict__ pooled, const float* __restrict__ gcnt,
                        const float* __restrict__ W_lin, const float* __restrict__ b_lin,
                        float* __restrict__ out) {
    int t = threadIdx.x;          // 256 = 128 graphs * 2 classes
    int g = t >> 1, c = t & 1;
    float inv = 1.0f / fmaxf(gcnt[g], 1.0f);
    float sum = b_lin[c];
    #pragma unroll 8
    for (int k = 0; k < HID; ++k)
        sum += pooled[g * HID + k] * inv * W_lin[c * HID + k];
    out[g * 2 + c] = sum;
}

extern "C" void kernel_launch(void* const* d_in, const int* in_sizes, int n_in,
                              void* d_out, int out_size, void* d_ws, size_t ws_size,
                              hipStream_t stream) {
    const int*   node_ids = (const int*)d_in[0];
    const int*   ei       = (const int*)d_in[1];
    const int*   batch    = (const int*)d_in[2];
    const float* table    = (const float*)d_in[3];
    const float* W1l      = (const float*)d_in[4];
    const float* W1r      = (const float*)d_in[5];
    const float* b1       = (const float*)d_in[6];
    const float* W2l      = (const float*)d_in[7];
    const float* W2r      = (const float*)d_in[8];
    const float* b2       = (const float*)d_in[9];
    const float* Wlin     = (const float*)d_in[10];
    const float* blin     = (const float*)d_in[11];
    const int* src = ei;
    const int* dst = ei + N_EDGES;

    float* ws     = (float*)d_ws;
    float* cnt    = ws;                                   // N
    float* agg32  = ws + N_NODES;                         // 32N
    float* agg64  = ws + 33 * N_NODES;                    // 64N
    float* pooled = ws + 97 * N_NODES;                    // 64G
    float* gcnt   = pooled + 64 * N_GRAPHS;               // G
    float* x0     = gcnt + N_GRAPHS;                      // 32N
    float* h1     = x0 + 32 * N_NODES;                    // 64N

    size_t zero_bytes = (size_t)(97 * N_NODES + 65 * N_GRAPHS) * sizeof(float);
    hipMemsetAsync(ws, 0, zero_bytes, stream);

    k_embed   <<<(N_NODES * 8 + 255) / 256, 256, 0, stream>>>(node_ids, table, x0);
    k_scatter1<<<(N_EDGES * 8) / 256,       256, 0, stream>>>(src, dst, x0, agg32, cnt);
    k_update1 <<<N_NODES / 4,               256, 0, stream>>>(agg32, cnt, x0, W1l, W1r, b1, h1);
    k_scatter2<<<(N_EDGES * 16) / 256,      256, 0, stream>>>(src, dst, h1, agg64);
    k_update2 <<<N_NODES / 4,               256, 0, stream>>>(agg64, cnt, h1, W2l, W2r, b2);
    k_pool    <<<2048,                      256, 0, stream>>>(agg64, batch, pooled, gcnt);
    k_final   <<<1,                         256, 0, stream>>>(pooled, gcnt, Wlin, blin, (float*)d_out);
}

// Round 2
// 557.662 us; speedup vs baseline: 3.9762x; 3.9762x over previous
//
#include <hip/hip_runtime.h>

#define N_NODES 100000
#define N_EDGES 1600000
#define N_GRAPHS 128
#define EMBED 32
#define HID 64
#define NB_SCAN 391   // ceil(N_NODES/256)

// ---------------- workspace layout ----------------
// ints : deg[N] cur[N] off[N] bsum[512] sorted_src[E]   (deg+cur zeroed per launch)
// float: x0[32N] h1[64N] h2[64N]
// total ~= 71.6 MB

// ---------- embed gather ----------
__global__ void k_embed(const int* __restrict__ ids,
                        const float* __restrict__ table,
                        float* __restrict__ x0) {
    int gid = blockIdx.x * blockDim.x + threadIdx.x;   // N*8 threads
    int n = gid >> 3, q = gid & 7;
    int id = ids[n];
    float4 v = *(const float4*)(table + id * EMBED + q * 4);
    *(float4*)(x0 + n * EMBED + q * 4) = v;
}

// ---------- counting sort: histogram ----------
__global__ void k_hist(const int* __restrict__ dst, int* __restrict__ deg) {
    int e = blockIdx.x * blockDim.x + threadIdx.x;
    if (e < N_EDGES) atomicAdd(&deg[dst[e]], 1);
}

// block-level exclusive scan (256/block)
__global__ void k_scan1(const int* __restrict__ deg, int* __restrict__ off,
                        int* __restrict__ bsum) {
    __shared__ int tmp[256];
    int i = blockIdx.x * 256 + threadIdx.x;
    int v = (i < N_NODES) ? deg[i] : 0;
    tmp[threadIdx.x] = v;
    __syncthreads();
    for (int d = 1; d < 256; d <<= 1) {
        int t = (threadIdx.x >= d) ? tmp[threadIdx.x - d] : 0;
        __syncthreads();
        tmp[threadIdx.x] += t;
        __syncthreads();
    }
    if (i < N_NODES) off[i] = tmp[threadIdx.x] - v;     // exclusive
    if (threadIdx.x == 255) bsum[blockIdx.x] = tmp[255];
}

__global__ void k_scan2(int* __restrict__ bsum) {       // 1 block, 512 thr
    __shared__ int tmp[512];
    int t = threadIdx.x;
    int v = (t < NB_SCAN) ? bsum[t] : 0;
    tmp[t] = v;
    __syncthreads();
    for (int d = 1; d < 512; d <<= 1) {
        int x = (t >= d) ? tmp[t - d] : 0;
        __syncthreads();
        tmp[t] += x;
        __syncthreads();
    }
    if (t < NB_SCAN) bsum[t] = tmp[t] - v;              // exclusive
}

__global__ void k_scan3(int* __restrict__ off, const int* __restrict__ bsum) {
    int i = blockIdx.x * 256 + threadIdx.x;
    if (i < N_NODES) off[i] += bsum[blockIdx.x];
}

// place edges into CSR order
__global__ void k_place(const int* __restrict__ src, const int* __restrict__ dst,
                        const int* __restrict__ off, int* __restrict__ cur,
                        int* __restrict__ sorted_src) {
    int e = blockIdx.x * blockDim.x + threadIdx.x;
    if (e >= N_EDGES) return;
    int d = dst[e];
    int pos = off[d] + atomicAdd(&cur[d], 1);
    sorted_src[pos] = src[e];
}

// ---------- conv1 fused: gather-mean + dual matvec + relu ----------
// 256 thr = 8 half-waves = 8 nodes/block
__global__ __launch_bounds__(256)
void k_conv1(const int* __restrict__ off, const int* __restrict__ deg,
             const int* __restrict__ sorted_src,
             const float* __restrict__ x0,
             const float* __restrict__ W_l, const float* __restrict__ W_r,
             const float* __restrict__ b, float* __restrict__ h1) {
    __shared__ float sWl[HID * 33];
    __shared__ float sWr[HID * 33];
    __shared__ float srow[8][64];      // [node][ mean(32) | x(32) ]
    for (int i = threadIdx.x; i < HID * EMBED; i += 256) {
        int o = i >> 5, k = i & 31;
        sWl[o * 33 + k] = W_l[i];
        sWr[o * 33 + k] = W_r[i];
    }
    int g = threadIdx.x >> 5, lane = threadIdx.x & 31;
    int n = blockIdx.x * 8 + g;
    int base = off[n], dg = deg[n];
    float acc = 0.0f;
    for (int j = 0; j < dg; ++j) {
        int s = sorted_src[base + j];
        acc += x0[s * EMBED + lane];
    }
    srow[g][lane]      = acc / fmaxf((float)dg, 1.0f);
    srow[g][32 + lane] = x0[n * EMBED + lane];
    __syncthreads();
    float sum0 = b[lane], sum1 = b[lane + 32];
    #pragma unroll
    for (int k = 0; k < EMBED; ++k) {
        float m  = srow[g][k];
        float xv = srow[g][32 + k];
        sum0 += m * sWl[lane * 33 + k]        + xv * sWr[lane * 33 + k];
        sum1 += m * sWl[(lane + 32) * 33 + k] + xv * sWr[(lane + 32) * 33 + k];
    }
    h1[n * HID + lane]      = fmaxf(sum0, 0.0f);
    h1[n * HID + lane + 32] = fmaxf(sum1, 0.0f);
}

// ---------- conv2 fused: gather-mean + dual matvec + relu ----------
// 512 thr = 8 waves = 8 nodes/block
__global__ __launch_bounds__(512)
void k_conv2(const int* __restrict__ off, const int* __restrict__ deg,
             const int* __restrict__ sorted_src,
             const float* __restrict__ h1,
             const float* __restrict__ W_l, const float* __restrict__ W_r,
             const float* __restrict__ b, float* __restrict__ h2) {
    __shared__ float sWl[HID * 65];
    __shared__ float sWr[HID * 65];
    __shared__ float srow[8][128];     // [node][ mean(64) | h1(64) ]
    for (int i = threadIdx.x; i < HID * HID; i += 512) {
        int o = i >> 6, k = i & 63;
        sWl[o * 65 + k] = W_l[i];
        sWr[o * 65 + k] = W_r[i];
    }
    int w = threadIdx.x >> 6, lane = threadIdx.x & 63;
    int n = blockIdx.x * 8 + w;
    int base = off[n], dg = deg[n];
    float acc = 0.0f;
    for (int j = 0; j < dg; ++j) {
        int s = sorted_src[base + j];
        acc += h1[s * HID + lane];
    }
    srow[w][lane]      = acc / fmaxf((float)dg, 1.0f);
    srow[w][64 + lane] = h1[n * HID + lane];
    __syncthreads();
    float sum = b[lane];
    #pragma unroll
    for (int k = 0; k < HID; ++k) {
        sum += srow[w][k]      * sWl[lane * 65 + k]
             + srow[w][64 + k] * sWr[lane * 65 + k];
    }
    h2[n * HID + lane] = fmaxf(sum, 0.0f);
}

// ---------- pool + final head, fused; one block per graph ----------
__device__ inline int lower_bound_batch(const int* b, int val) {
    int lo = 0, hi = N_NODES;
    while (lo < hi) {
        int mid = (lo + hi) >> 1;
        if (b[mid] < val) lo = mid + 1; else hi = mid;
    }
    return lo;
}

__global__ __launch_bounds__(256)
void k_pool_final(const float* __restrict__ h2, const int* __restrict__ batch,
                  const float* __restrict__ W_lin, const float* __restrict__ b_lin,
                  float* __restrict__ out) {
    __shared__ float red[4][64];
    __shared__ float pool[64];
    int g = blockIdx.x;
    int start = lower_bound_batch(batch, g);
    int end   = lower_bound_batch(batch, g + 1);
    int w = threadIdx.x >> 6, lane = threadIdx.x & 63;
    float acc = 0.0f;
    for (int n = start + w; n < end; n += 4)
        acc += h2[n * HID + lane];
    red[w][lane] = acc;
    __syncthreads();
    if (w == 0) {
        float tot = red[0][lane] + red[1][lane] + red[2][lane] + red[3][lane];
        pool[lane] = tot / fmaxf((float)(end - start), 1.0f);
    }
    __syncthreads();
    if (threadIdx.x < 2) {
        int c = threadIdx.x;
        float s = b_lin[c];
        #pragma unroll 8
        for (int k = 0; k < HID; ++k)
            s += pool[k] * W_lin[c * HID + k];
        out[g * 2 + c] = s;
    }
}

extern "C" void kernel_launch(void* const* d_in, const int* in_sizes, int n_in,
                              void* d_out, int out_size, void* d_ws, size_t ws_size,
                              hipStream_t stream) {
    const int*   node_ids = (const int*)d_in[0];
    const int*   ei       = (const int*)d_in[1];
    const int*   batch    = (const int*)d_in[2];
    const float* table    = (const float*)d_in[3];
    const float* W1l      = (const float*)d_in[4];
    const float* W1r      = (const float*)d_in[5];
    const float* b1       = (const float*)d_in[6];
    const float* W2l      = (const float*)d_in[7];
    const float* W2r      = (const float*)d_in[8];
    const float* b2       = (const float*)d_in[9];
    const float* Wlin     = (const float*)d_in[10];
    const float* blin     = (const float*)d_in[11];
    const int* src = ei;
    const int* dst = ei + N_EDGES;

    int* ideg = (int*)d_ws;                    // N
    int* icur = ideg + N_NODES;                // N
    int* ioff = icur + N_NODES;                // N
    int* ibsum = ioff + N_NODES;               // 512
    int* isrc = ibsum + 512;                   // E
    float* x0 = (float*)(isrc + N_EDGES);      // 32N  (16B-aligned: 1900512*4 % 16 == 0)
    float* h1 = x0 + 32 * N_NODES;             // 64N
    float* h2 = h1 + 64 * N_NODES;             // 64N

    hipMemsetAsync(ideg, 0, 2 * N_NODES * sizeof(int), stream);  // deg + cur

    k_embed<<<N_NODES * 8 / 256, 256, 0, stream>>>(node_ids, table, x0);
    k_hist <<<(N_EDGES + 255) / 256, 256, 0, stream>>>(dst, ideg);
    k_scan1<<<NB_SCAN, 256, 0, stream>>>(ideg, ioff, ibsum);
    k_scan2<<<1, 512, 0, stream>>>(ibsum);
    k_scan3<<<NB_SCAN, 256, 0, stream>>>(ioff, ibsum);
    k_place<<<(N_EDGES + 255) / 256, 256, 0, stream>>>(src, dst, ioff, icur, isrc);
    k_conv1<<<N_NODES / 8, 256, 0, stream>>>(ioff, ideg, isrc, x0, W1l, W1r, b1, h1);
    k_conv2<<<N_NODES / 8, 512, 0, stream>>>(ioff, ideg, isrc, h1, W2l, W2r, b2, h2);
    k_pool_final<<<N_GRAPHS, 256, 0, stream>>>(h2, batch, Wlin, blin, (float*)d_out);
}

// Round 3
// 412.217 us; speedup vs baseline: 5.3791x; 1.3528x over previous
//
#include <hip/hip_runtime.h>
#include <hip/hip_fp16.h>

#define N_NODES 100000
#define N_EDGES 1600000
#define N_GRAPHS 128
#define EMBED 32
#define HID 64
#define NB_SCAN 391            // ceil(N_NODES/256)
#define CHUNK 128              // edges per group (E % CHUNK == 0)
#define NGRP (N_EDGES / CHUNK) // 12500

// ---------------- workspace layout ----------------
// ints : deg[N] cur[N] off[N+1] bsum[512] ssrc[E]
// fp32 : aggAB[64N]   (agg1 = first 32N, agg2 = all 64N; re-zeroed between)
// fp16 : x0h[32N] h1h[64N] h2h[64N]
// total ~= 65.2 MB

// ---------- embed gather -> fp16 ----------
__global__ void k_embed(const int* __restrict__ ids,
                        const float* __restrict__ table,
                        __half2* __restrict__ x0h) {
    int gid = blockIdx.x * blockDim.x + threadIdx.x;   // N*16 threads
    int n = gid >> 4, q = gid & 15;
    int id = ids[n];
    float2 t = ((const float2*)(table + id * EMBED))[q];
    x0h[n * 16 + q] = __floats2half2_rn(t.x, t.y);
}

// ---------- counting sort ----------
__global__ void k_hist(const int* __restrict__ dst, int* __restrict__ deg) {
    int e = blockIdx.x * blockDim.x + threadIdx.x;
    if (e < N_EDGES) atomicAdd(&deg[dst[e]], 1);
}

__global__ void k_scan1(const int* __restrict__ deg, int* __restrict__ off,
                        int* __restrict__ bsum) {
    __shared__ int tmp[256];
    int i = blockIdx.x * 256 + threadIdx.x;
    int v = (i < N_NODES) ? deg[i] : 0;
    tmp[threadIdx.x] = v;
    __syncthreads();
    for (int d = 1; d < 256; d <<= 1) {
        int t = (threadIdx.x >= d) ? tmp[threadIdx.x - d] : 0;
        __syncthreads();
        tmp[threadIdx.x] += t;
        __syncthreads();
    }
    if (i < N_NODES) off[i] = tmp[threadIdx.x] - v;
    if (threadIdx.x == 255) bsum[blockIdx.x] = tmp[255];
}

__global__ void k_scan2(int* __restrict__ bsum) {
    __shared__ int tmp[512];
    int t = threadIdx.x;
    int v = (t < NB_SCAN) ? bsum[t] : 0;
    tmp[t] = v;
    __syncthreads();
    for (int d = 1; d < 512; d <<= 1) {
        int x = (t >= d) ? tmp[t - d] : 0;
        __syncthreads();
        tmp[t] += x;
        __syncthreads();
    }
    if (t < NB_SCAN) bsum[t] = tmp[t] - v;
}

__global__ void k_scan3(int* __restrict__ off, const int* __restrict__ bsum) {
    int i = blockIdx.x * 256 + threadIdx.x;
    if (i < N_NODES) off[i] += bsum[blockIdx.x];
    if (blockIdx.x == 0 && threadIdx.x == 0) off[N_NODES] = N_EDGES;
}

__global__ void k_place(const int* __restrict__ src, const int* __restrict__ dst,
                        const int* __restrict__ off, int* __restrict__ cur,
                        int* __restrict__ sorted_src) {
    int e = blockIdx.x * blockDim.x + threadIdx.x;
    if (e >= N_EDGES) return;
    int d = dst[e];
    int pos = off[d] + atomicAdd(&cur[d], 1);
    sorted_src[pos] = src[e];
}

// ---------- edge-streaming segmented aggregation ----------
// L lanes per group; feature row = L half2 (=2L channels); group owns CHUNK edges.
// Direct store for dsts fully inside the slice; atomics only at boundaries.
template<int L>
__global__ __launch_bounds__(256)
void k_agg(const int* __restrict__ ssrc, const int* __restrict__ off,
           const __half2* __restrict__ feat,   // [N][L] half2
           float2* __restrict__ agg)           // [N][L] float2
{
    int tid = blockIdx.x * 256 + threadIdx.x;
    int grp = tid / L;
    int lane = tid % L;
    if (grp >= NGRP) return;
    int base = grp * CHUNK;
    int end  = base + CHUNK;
    // largest d with off[d] <= base  (then off[d] <= base < off[d+1])
    int lo = 0, hi = N_NODES - 1;
    while (lo < hi) {
        int mid = (lo + hi + 1) >> 1;
        if (off[mid] <= base) lo = mid; else hi = mid - 1;
    }
    int d = lo;
    bool dstart_in = (off[d] >= base);        // false -> partial (atomic flush)
    int next = off[d + 1];
    float2 acc = make_float2(0.f, 0.f);
    for (int j = base; j < end; j += 4) {
        int s0 = ssrc[j], s1 = ssrc[j + 1], s2 = ssrc[j + 2], s3 = ssrc[j + 3];
        __half2 v0 = feat[s0 * L + lane];
        __half2 v1 = feat[s1 * L + lane];
        __half2 v2 = feat[s2 * L + lane];
        __half2 v3 = feat[s3 * L + lane];
        #pragma unroll
        for (int q = 0; q < 4; ++q) {
            int jj = j + q;
            if (jj >= next) {                 // flush d before edge jj
                if (dstart_in) {
                    agg[d * L + lane] = acc;
                } else {
                    unsafeAtomicAdd(&((float*)agg)[(d * L + lane) * 2],     acc.x);
                    unsafeAtomicAdd(&((float*)agg)[(d * L + lane) * 2 + 1], acc.y);
                }
                acc = make_float2(0.f, 0.f);
                dstart_in = true;
                d++;
                while (off[d + 1] <= jj) d++; // skip deg-0 nodes
                next = off[d + 1];
            }
            __half2 v = (q == 0) ? v0 : (q == 1) ? v1 : (q == 2) ? v2 : v3;
            float2 f = __half22float2(v);
            acc.x += f.x; acc.y += f.y;
        }
    }
    if (dstart_in && next == end) {           // ends exactly at slice end
        agg[d * L + lane] = acc;
    } else {
        unsafeAtomicAdd(&((float*)agg)[(d * L + lane) * 2],     acc.x);
        unsafeAtomicAdd(&((float*)agg)[(d * L + lane) * 2 + 1], acc.y);
    }
}

// ---------- dense update 1: h1 = relu(mean@W1l.T + x0@W1r.T + b)  (4 nodes/wave) ----------
__global__ __launch_bounds__(512)
void k_update1(const float* __restrict__ agg1,   // [N][32] sums
               const int* __restrict__ deg,
               const __half2* __restrict__ x0h,  // [N][16]
               const float* __restrict__ W_l, const float* __restrict__ W_r,
               const float* __restrict__ b,
               __half* __restrict__ h1h)         // [N][64]
{
    __shared__ float sWl[HID * 34];
    __shared__ float sWr[HID * 34];
    __shared__ float srow[8][4][64];             // [wave][node][mean32|own32]
    for (int i = threadIdx.x; i < HID * EMBED; i += 512) {
        int o = i >> 5, k = i & 31;
        sWl[o * 34 + k] = W_l[i];
        sWr[o * 34 + k] = W_r[i];
    }
    int w = threadIdx.x >> 6, lane = threadIdx.x & 63;
    int nb = blockIdx.x * 32 + w * 4;
    #pragma unroll
    for (int i = 0; i < 4; ++i) {
        int n = nb + i;
        if (lane < 32) {
            float inv = 1.0f / fmaxf((float)deg[n], 1.0f);
            srow[w][i][lane] = agg1[n * 32 + lane] * inv;
        } else {
            int ch = lane - 32;
            float2 f = __half22float2(x0h[n * 16 + (ch >> 1)]);
            srow[w][i][lane] = ((ch & 1) == 0) ? f.x : f.y;
        }
    }
    __syncthreads();
    float bo = b[lane];
    float a0 = 0, a1 = 0, a2 = 0, a3 = 0;
    #pragma unroll
    for (int k = 0; k < 32; ++k) {
        float wl = sWl[lane * 34 + k];
        float wr = sWr[lane * 34 + k];
        a0 += srow[w][0][k] * wl + srow[w][0][32 + k] * wr;
        a1 += srow[w][1][k] * wl + srow[w][1][32 + k] * wr;
        a2 += srow[w][2][k] * wl + srow[w][2][32 + k] * wr;
        a3 += srow[w][3][k] * wl + srow[w][3][32 + k] * wr;
    }
    h1h[(nb + 0) * HID + lane] = __float2half(fmaxf(a0 + bo, 0.f));
    h1h[(nb + 1) * HID + lane] = __float2half(fmaxf(a1 + bo, 0.f));
    h1h[(nb + 2) * HID + lane] = __float2half(fmaxf(a2 + bo, 0.f));
    h1h[(nb + 3) * HID + lane] = __float2half(fmaxf(a3 + bo, 0.f));
}

// ---------- dense update 2: h2 = relu(mean@W2l.T + h1@W2r.T + b)  (4 nodes/wave) ----------
__global__ __launch_bounds__(512)
void k_update2(const float* __restrict__ agg2,   // [N][64] sums
               const int* __restrict__ deg,
               const __half* __restrict__ h1h,   // [N][64]
               const float* __restrict__ W_l, const float* __restrict__ W_r,
               const float* __restrict__ b,
               __half* __restrict__ h2h)         // [N][64]
{
    __shared__ float sWl[HID * 66];
    __shared__ float sWr[HID * 66];
    __shared__ float srow[8][4][128];            // [wave][node][mean64|own64]
    for (int i = threadIdx.x; i < HID * HID; i += 512) {
        int o = i >> 6, k = i & 63;
        sWl[o * 66 + k] = W_l[i];
        sWr[o * 66 + k] = W_r[i];
    }
    int w = threadIdx.x >> 6, lane = threadIdx.x & 63;
    int nb = blockIdx.x * 32 + w * 4;
    #pragma unroll
    for (int i = 0; i < 4; ++i) {
        int n = nb + i;
        float inv = 1.0f / fmaxf((float)deg[n], 1.0f);
        srow[w][i][lane]      = agg2[n * 64 + lane] * inv;
        srow[w][i][64 + lane] = __half2float(h1h[n * 64 + lane]);
    }
    __syncthreads();
    float bo = b[lane];
    float a0 = 0, a1 = 0, a2 = 0, a3 = 0;
    #pragma unroll
    for (int k = 0; k < 64; ++k) {
        float wl = sWl[lane * 66 + k];
        float wr = sWr[lane * 66 + k];
        a0 += srow[w][0][k] * wl + srow[w][0][64 + k] * wr;
        a1 += srow[w][1][k] * wl + srow[w][1][64 + k] * wr;
        a2 += srow[w][2][k] * wl + srow[w][2][64 + k] * wr;
        a3 += srow[w][3][k] * wl + srow[w][3][64 + k] * wr;
    }
    h2h[(nb + 0) * HID + lane] = __float2half(fmaxf(a0 + bo, 0.f));
    h2h[(nb + 1) * HID + lane] = __float2half(fmaxf(a1 + bo, 0.f));
    h2h[(nb + 2) * HID + lane] = __float2half(fmaxf(a2 + bo, 0.f));
    h2h[(nb + 3) * HID + lane] = __float2half(fmaxf(a3 + bo, 0.f));
}

// ---------- pool + final head ----------
__device__ inline int lower_bound_batch(const int* b, int val) {
    int lo = 0, hi = N_NODES;
    while (lo < hi) {
        int mid = (lo + hi) >> 1;
        if (b[mid] < val) lo = mid + 1; else hi = mid;
    }
    return lo;
}

__global__ __launch_bounds__(256)
void k_pool_final(const __half* __restrict__ h2h, const int* __restrict__ batch,
                  const float* __restrict__ W_lin, const float* __restrict__ b_lin,
                  float* __restrict__ out) {
    __shared__ float red[4][64];
    __shared__ float pool[64];
    int g = blockIdx.x;
    int start = lower_bound_batch(batch, g);
    int end   = lower_bound_batch(batch, g + 1);
    int w = threadIdx.x >> 6, lane = threadIdx.x & 63;
    float acc = 0.0f;
    for (int n = start + w; n < end; n += 4)
        acc += __half2float(h2h[n * HID + lane]);
    red[w][lane] = acc;
    __syncthreads();
    if (w == 0) {
        float tot = red[0][lane] + red[1][lane] + red[2][lane] + red[3][lane];
        pool[lane] = tot / fmaxf((float)(end - start), 1.0f);
    }
    __syncthreads();
    if (threadIdx.x < 2) {
        int c = threadIdx.x;
        float s = b_lin[c];
        #pragma unroll 8
        for (int k = 0; k < HID; ++k)
            s += pool[k] * W_lin[c * HID + k];
        out[g * 2 + c] = s;
    }
}

extern "C" void kernel_launch(void* const* d_in, const int* in_sizes, int n_in,
                              void* d_out, int out_size, void* d_ws, size_t ws_size,
                              hipStream_t stream) {
    const int*   node_ids = (const int*)d_in[0];
    const int*   ei       = (const int*)d_in[1];
    const int*   batch    = (const int*)d_in[2];
    const float* table    = (const float*)d_in[3];
    const float* W1l      = (const float*)d_in[4];
    const float* W1r      = (const float*)d_in[5];
    const float* b1       = (const float*)d_in[6];
    const float* W2l      = (const float*)d_in[7];
    const float* W2r      = (const float*)d_in[8];
    const float* b2       = (const float*)d_in[9];
    const float* Wlin     = (const float*)d_in[10];
    const float* blin     = (const float*)d_in[11];
    const int* src = ei;
    const int* dst = ei + N_EDGES;

    int* ideg  = (int*)d_ws;                   // N
    int* icur  = ideg + N_NODES;               // N
    int* ioff  = icur + N_NODES;               // N+1
    int* ibsum = ioff + N_NODES + 1;           // 512
    int* issrc = ibsum + 512;                  // E
    // 16-byte aligned: 1900513 ints -> pad to 1900516
    float*   aggAB = (float*)(issrc + N_EDGES) + 3;    // 64N floats (agg1 = first 32N)
    __half2* x0h   = (__half2*)(aggAB + 64 * N_NODES); // 16N half2
    __half*  h1h   = (__half*)(x0h + 16 * N_NODES);    // 64N half
    __half*  h2h   = h1h + 64 * N_NODES;               // 64N half

    // zero: deg+cur, and agg1 region
    hipMemsetAsync(ideg, 0, 2 * N_NODES * sizeof(int), stream);
    hipMemsetAsync(aggAB, 0, 32 * N_NODES * sizeof(float), stream);

    k_embed<<<N_NODES * 16 / 256, 256, 0, stream>>>(node_ids, table, x0h);
    k_hist <<<(N_EDGES + 255) / 256, 256, 0, stream>>>(dst, ideg);
    k_scan1<<<NB_SCAN, 256, 0, stream>>>(ideg, ioff, ibsum);
    k_scan2<<<1, 512, 0, stream>>>(ibsum);
    k_scan3<<<NB_SCAN, 256, 0, stream>>>(ioff, ibsum);
    k_place<<<(N_EDGES + 255) / 256, 256, 0, stream>>>(src, dst, ioff, icur, issrc);

    k_agg<16><<<(NGRP * 16 + 255) / 256, 256, 0, stream>>>(issrc, ioff, x0h,
                                                           (float2*)aggAB);
    k_update1<<<N_NODES / 32, 512, 0, stream>>>(aggAB, ideg, x0h, W1l, W1r, b1, h1h);

    hipMemsetAsync(aggAB, 0, 64 * N_NODES * sizeof(float), stream);
    k_agg<32><<<(NGRP * 32 + 255) / 256, 256, 0, stream>>>(issrc, ioff,
                                                           (const __half2*)h1h,
                                                           (float2*)aggAB);
    k_update2<<<N_NODES / 32, 512, 0, stream>>>(aggAB, ideg, h1h, W2l, W2r, b2, h2h);

    k_pool_final<<<N_GRAPHS, 256, 0, stream>>>(h2h, batch, Wlin, blin, (float*)d_out);
}